// Round 12
// baseline (371.698 us; speedup 1.0000x reference)
//
#include <hip/hip_runtime.h>
#include <hip/hip_bf16.h>

// ---------------------------------------------------------------------------
// TileSelfAttention, round 12.
// QKV GEMM: dual-digit int8 MFMA (exact i32 acc).
//   OCCUPANCY EXPERIMENT: tile 128x64, 4-wave blocks (wave tile 64x32),
//   dual acc = 64 AGPR + ~90 VGPR -> 3 waves/SIMD; LDS 48KB -> 3 blocks/CU
//   (12 waves/CU, was 8).  Chunk skeleton = R6/R9 proven: fragment-order LDS
//   (0 conflicts), 1 vmcnt(0)+barrier per chunk, stages issued a full chunk
//   ahead, alpha/beta/gamma register reuse.
// ---------------------------------------------------------------------------

typedef __bf16 bf16;
using i32x4 = __attribute__((ext_vector_type(4))) int;

#define NT     64
#define BATCH  512

#define OFF_XQH 0ul
#define OFF_XQL 33554432ul
#define OFF_WT  67108864ul
#define OFF_K   70254592ul
#define OFF_Q   137363456ul
#define OFF_V   204472320ul
#define OFF_AW  271581184ul
#define OFF_MS  279969792ul

// ---------------------------------------------------------------------------
__global__ void quant_kernel(const float* __restrict__ x,
                             unsigned int* __restrict__ qh,
                             unsigned int* __restrict__ ql, int n4, float invS) {
  int i = blockIdx.x * blockDim.x + threadIdx.x;
  int stride = gridDim.x * blockDim.x;
  for (; i < n4; i += stride) {
    float4 v = ((const float4*)x)[i];
    unsigned hw = 0, lw = 0;
#pragma unroll
    for (int j = 0; j < 4; ++j) {
      float f = (j == 0) ? v.x : (j == 1) ? v.y : (j == 2) ? v.z : v.w;
      int q = __float2int_rn(f * invS);
      q = max(-16320, min(16319, q));
      int h = (q + 64) >> 7;
      int lo = q - (h << 7);
      hw |= ((unsigned)(h & 0xFF)) << (8 * j);
      lw |= ((unsigned)(lo & 0xFF)) << (8 * j);
    }
    qh[i] = hw;
    ql[i] = lw;
  }
}

// ---------------------------------------------------------------------------
// quantize W into fragment-tiled layout (all 3 projections, one launch):
//   WT[proj] : offset = ((ct*16 + kc)*2048) + plane*1024 + lane*16 + ki
// ---------------------------------------------------------------------------
__global__ void quant_w_kernel(const float* __restrict__ W0,
                               const float* __restrict__ W1,
                               const float* __restrict__ W2,
                               char* __restrict__ WT, float invS) {
  int gid = blockIdx.x * blockDim.x + threadIdx.x;  // 0..393215
  int proj = gid >> 17;
  int idx = gid & 131071;
  const float* W = (proj == 0) ? W0 : (proj == 1 ? W1 : W2);
  int c = idx >> 8, k = (idx & 255) * 4;
  float4 v = ((const float4*)W)[idx];
  unsigned hw = 0, lw = 0;
#pragma unroll
  for (int j = 0; j < 4; ++j) {
    float f = (j == 0) ? v.x : (j == 1) ? v.y : (j == 2) ? v.z : v.w;
    int q = __float2int_rn(f * invS);
    q = max(-16320, min(16319, q));
    int h = (q + 64) >> 7;
    int lo = q - (h << 7);
    hw |= ((unsigned)(h & 0xFF)) << (8 * j);
    lw |= ((unsigned)(lo & 0xFF)) << (8 * j);
  }
  int kc = k >> 6, kg = (k >> 4) & 3, ki = k & 15;
  int ct = c >> 4, lane = (c & 15) | (kg << 4);
  size_t dst = (size_t)proj * 1048576 + (size_t)(ct * 16 + kc) * 2048 +
               lane * 16 + ki;
  *(unsigned int*)(WT + dst) = hw;          // ph plane
  *(unsigned int*)(WT + dst + 1024) = lw;   // pl plane
}

// ---------------------------------------------------------------------------
__device__ __forceinline__ void gl16(const char* g, char* l) {
  __builtin_amdgcn_global_load_lds(
      (const __attribute__((address_space(1))) unsigned int*)g,
      (__attribute__((address_space(3))) unsigned int*)l, 16, 0, 0);
}

#define VMCNT0 asm volatile("s_waitcnt vmcnt(0)" ::: "memory")
#define BAR    __builtin_amdgcn_s_barrier()
#define MFMA8  __builtin_amdgcn_mfma_i32_16x16x64_i8

__global__ __launch_bounds__(256, 3) void gemm_i8(
    const char* __restrict__ XQH, const char* __restrict__ XQL,
    const char* __restrict__ WT,
    const float* __restrict__ bk, const float* __restrict__ bq,
    const float* __restrict__ bv,
    float* __restrict__ K, float* __restrict__ Q, float* __restrict__ V) {
  __shared__ __align__(16) char lds[49152];  // 2 x 24KB
  // per buffer: Aqh [0,8K) Aql [8K,16K) Bph [16K,20K) Bpl [20K,24K)
  // fragment order: tile*1024 + lane*16 (A: 8 m-tiles, B: 4 n-tiles)

  // T1: bijective XCD swizzle (6144 = 8 * 768); mt-major for A-panel reuse
  const int bid = (blockIdx.x & 7) * 768 + (blockIdx.x >> 3);
  const int mt = bid / 24, nb = bid % 24;
  const int gm0 = mt * 128;
  const int proj = nb >> 3;
  const int nt8 = nb & 7;            // 64-col n-block within projection
  const int wn0 = nt8 * 64;

  const int tid = threadIdx.x;
  const int l = tid & 63, w = tid >> 6;  // 4 waves: 2M x 2N
  const int wr = w >> 1, wc = w & 1;     // wave tile 64x32
  const int lr = l & 15, lk = l >> 4;

  // A staging src (fragment-order): unit u = tid -> mtiles 0..3, +256 -> 4..7
  const size_t aoff0 = (size_t)(gm0 + ((tid >> 6) << 4) + (tid & 15)) * 1024 +
                       (((tid >> 4) & 3) << 4);
  const char* aqh0 = XQH + aoff0;
  const char* aql0 = XQL + aoff0;
  // B staging src from pre-tiled WT: ct = nt8*4 + (tid>>6), lane = tid&63
  const char* wph0 = WT + (size_t)proj * 1048576 +
                     (size_t)(nt8 * 4 + (tid >> 6)) * 32768 + (tid & 63) * 16;
  const char* wpl0 = wph0 + 1024;
  const int dT = tid * 16;

  // fragment read bases (wave-sequential 1KB -> conflict-free)
  const int rdA = wr * 4096 + l * 16;            // + mf*1024 ; ql +8192
  const int rdB = 16384 + wc * 2048 + l * 16;    // + nf*1024 ; pl +4096

  i32x4 acc1[4][2] = {};
  i32x4 acc2[4][2] = {};

  auto STAGE = [&](int kc, int bo) {
    const int kA = kc * 64, kB = kc * 2048;
    gl16(aqh0 + kA, lds + bo + dT);
    gl16(aqh0 + 65536 + kA, lds + bo + 4096 + dT);
    gl16(aql0 + kA, lds + bo + 8192 + dT);
    gl16(aql0 + 65536 + kA, lds + bo + 12288 + dT);
    gl16(wph0 + kB, lds + bo + 16384 + dT);
    gl16(wpl0 + kB, lds + bo + 20480 + dT);
  };

  STAGE(0, 0);

  for (int kc = 0; kc < 16; ++kc) {
    const int bo = (kc & 1) * 24576;
    VMCNT0;  // own chunk-kc stages done (issued a full chunk ago)
    BAR;     // all waves' stages landed; prev-chunk reads retired
    if (kc < 15) STAGE(kc + 1, bo ^ 24576);

    i32x4 aH[4], aL[4], bH[2], bL[2];
#pragma unroll
    for (int mf = 0; mf < 4; ++mf)
      aH[mf] = *(const i32x4*)(lds + bo + rdA + mf * 1024);
#pragma unroll
    for (int nf = 0; nf < 2; ++nf)
      bL[nf] = *(const i32x4*)(lds + bo + rdB + nf * 1024 + 4096);

    __builtin_amdgcn_s_setprio(1);
#pragma unroll
    for (int mf = 0; mf < 4; ++mf)   // alpha: qh . pl -> acc2
#pragma unroll
      for (int nf = 0; nf < 2; ++nf)
        acc2[mf][nf] = MFMA8(aH[mf], bL[nf], acc2[mf][nf], 0, 0, 0);
    __builtin_amdgcn_s_setprio(0);

#pragma unroll
    for (int nf = 0; nf < 2; ++nf)
      bH[nf] = *(const i32x4*)(lds + bo + rdB + nf * 1024);

    __builtin_amdgcn_s_setprio(1);
#pragma unroll
    for (int mf = 0; mf < 4; ++mf)   // beta: qh . ph -> acc1 (reuse aH)
#pragma unroll
      for (int nf = 0; nf < 2; ++nf)
        acc1[mf][nf] = MFMA8(aH[mf], bH[nf], acc1[mf][nf], 0, 0, 0);
    __builtin_amdgcn_s_setprio(0);

#pragma unroll
    for (int mf = 0; mf < 4; ++mf)
      aL[mf] = *(const i32x4*)(lds + bo + rdA + mf * 1024 + 8192);

    __builtin_amdgcn_s_setprio(1);
#pragma unroll
    for (int mf = 0; mf < 4; ++mf)   // gamma: ql . ph -> acc2 (reuse bH)
#pragma unroll
      for (int nf = 0; nf < 2; ++nf)
        acc2[mf][nf] = MFMA8(aL[mf], bH[nf], acc2[mf][nf], 0, 0, 0);
    __builtin_amdgcn_s_setprio(0);
  }

  // epilogue: Out = XS*WS*(16384*acc1 + 128*acc2) + bias
  const float SC = (6.0f / 16256.0f) * (0.03125f / 16320.0f);
  const float* bias = (proj == 0) ? bk : (proj == 1 ? bq : bv);
  float* Out = (proj == 0) ? K : (proj == 1 ? Q : V);
#pragma unroll
  for (int mf = 0; mf < 4; ++mf) {
    const int row0 = gm0 + wr * 64 + mf * 16 + lk * 4;
#pragma unroll
    for (int nf = 0; nf < 2; ++nf) {
      const int col = wn0 + wc * 32 + nf * 16 + lr;
      const float bb = bias[col];
#pragma unroll
      for (int r = 0; r < 4; ++r)
        Out[(size_t)(row0 + r) * 512 + col] =
            fmaf(16384.f, (float)acc1[mf][nf][r],
                 128.f * (float)acc2[mf][nf][r]) * SC + bb;
    }
  }
}

// ---------------------------------------------------------------------------
// logits: AW[b,t,s] = (1/sqrt(512)) * sum_c K[b*64+t,c] * Q[b*64+s,c]
// ---------------------------------------------------------------------------
__global__ __launch_bounds__(256) void logits_kernel(
    const float* __restrict__ K, const float* __restrict__ Q,
    float* __restrict__ AW) {
  __shared__ float Ks[64][68];
  __shared__ float Qs[64][68];
  const int b = blockIdx.x;
  const float* Kb = K + (size_t)b * 32768;
  const float* Qb = Q + (size_t)b * 32768;
  const int tid = threadIdx.x;
  const int tr = tid >> 4, tc = tid & 15;

  float acc[4][4] = {};
  for (int c0 = 0; c0 < 512; c0 += 64) {
    __syncthreads();
#pragma unroll
    for (int i = 0; i < 4; ++i) {
      int idx = tid + i * 256;
      int row = idx >> 4;
      int c4 = (idx & 15) * 4;
      float4 kv = *(const float4*)&Kb[row * 512 + c0 + c4];
      float4 qv = *(const float4*)&Qb[row * 512 + c0 + c4];
      Ks[c4 + 0][row] = kv.x; Ks[c4 + 1][row] = kv.y;
      Ks[c4 + 2][row] = kv.z; Ks[c4 + 3][row] = kv.w;
      Qs[c4 + 0][row] = qv.x; Qs[c4 + 1][row] = qv.y;
      Qs[c4 + 2][row] = qv.z; Qs[c4 + 3][row] = qv.w;
    }
    __syncthreads();
#pragma unroll 4
    for (int cc = 0; cc < 64; ++cc) {
      float4 kx = *(const float4*)&Ks[cc][tr * 4];
      float4 qx = *(const float4*)&Qs[cc][tc * 4];
#pragma unroll
      for (int i = 0; i < 4; ++i)
#pragma unroll
        for (int j = 0; j < 4; ++j) acc[i][j] += kx[i] * qx[j];
    }
  }
  const float scale = 0.04419417382415922f;
#pragma unroll
  for (int i = 0; i < 4; ++i)
#pragma unroll
    for (int j = 0; j < 4; ++j)
      AW[(size_t)b * 4096 + (tr * 4 + i) * 64 + (tc * 4 + j)] =
          acc[i][j] * scale;
}

// ---------------------------------------------------------------------------
// stats over batch axis: for each (t,s), m = max_b, inv = 1/sum_b exp(l-m).
// ---------------------------------------------------------------------------
__global__ __launch_bounds__(1024) void stats_kernel(
    const float* __restrict__ AW, float* __restrict__ M,
    float* __restrict__ I) {
  __shared__ float red[16][64];
  const int tt = blockIdx.x;
  const int tid = threadIdx.x;
  const int s = tid & 63, bq = tid >> 6;
  const size_t base = (size_t)tt * 64 + s;

  float m = -3.4e38f;
  for (int b = bq * 32; b < bq * 32 + 32; ++b)
    m = fmaxf(m, AW[(size_t)b * 4096 + base]);
  red[bq][s] = m;
  __syncthreads();
#pragma unroll
  for (int i = 0; i < 16; ++i) m = fmaxf(m, red[i][s]);
  __syncthreads();

  float sum = 0.f;
  for (int b = bq * 32; b < bq * 32 + 32; ++b)
    sum += __expf(AW[(size_t)b * 4096 + base] - m);
  red[bq][s] = sum;
  __syncthreads();
  if (bq == 0) {
    sum = 0.f;
#pragma unroll
    for (int i = 0; i < 16; ++i) sum += red[i][s];
    M[tt * 64 + s] = m;
    I[tt * 64 + s] = 1.0f / sum;
  }
}

// ---------------------------------------------------------------------------
// out[b,c,s] = sum_t V[b*64+t, c] * p,  p = exp(AW[b,t,s]-M[t,s])*I[t,s]
// ---------------------------------------------------------------------------
__global__ __launch_bounds__(512) void out_kernel(
    const float* __restrict__ V, const float* __restrict__ AW,
    const float* __restrict__ M, const float* __restrict__ I,
    float* __restrict__ out) {
  __shared__ float Vs[32768];    // [t][c] flat, 128KB
  __shared__ float Ps[64][65];   // 16.25KB
  const int b = blockIdx.x;
  const int tid = threadIdx.x;
  const float* Vb = V + (size_t)b * 32768;
  const float* Pb = AW + (size_t)b * 4096;

#pragma unroll
  for (int j = 0; j < 16; ++j) {
    int u = j * 512 + tid;
    ((float4*)Vs)[u] = ((const float4*)Vb)[u];
  }
  for (int i = tid; i < 4096; i += 512)
    Ps[i >> 6][i & 63] = __expf(Pb[i] - M[i]) * I[i];
  __syncthreads();

  const int s = tid & 63, cw = tid >> 6;  // cw 0..7
  const int c0 = cw * 64;
  float a[64] = {};
  for (int t = 0; t < 64; ++t) {
    float p = Ps[t][s];
    const float4* vr = (const float4*)(Vs + t * 512 + c0);
#pragma unroll
    for (int j = 0; j < 16; ++j) {
      float4 v = vr[j];
      a[4 * j + 0] += v.x * p;
      a[4 * j + 1] += v.y * p;
      a[4 * j + 2] += v.z * p;
      a[4 * j + 3] += v.w * p;
    }
  }
  float* Ob = out + (size_t)b * 32768;
#pragma unroll
  for (int j = 0; j < 64; ++j)
    Ob[(size_t)(c0 + j) * 64 + s] = a[j];
}

// ---------------------------------------------------------------------------
extern "C" void kernel_launch(void* const* d_in, const int* in_sizes, int n_in,
                              void* d_out, int out_size, void* d_ws,
                              size_t ws_size, hipStream_t stream) {
  const float* x  = (const float*)d_in[0];
  const float* Wk = (const float*)d_in[1];
  const float* bk = (const float*)d_in[2];
  const float* Wq = (const float*)d_in[3];
  const float* bq = (const float*)d_in[4];
  const float* Wv = (const float*)d_in[5];
  const float* bv = (const float*)d_in[6];
  float* out = (float*)d_out;

  char* ws = (char*)d_ws;
  unsigned int* XQH = (unsigned int*)(ws + OFF_XQH);
  unsigned int* XQL = (unsigned int*)(ws + OFF_XQL);
  char* WT = ws + OFF_WT;
  float* K  = (float*)(ws + OFF_K);
  float* Q  = (float*)(ws + OFF_Q);
  float* V  = (float*)(ws + OFF_V);
  float* AW = (float*)(ws + OFF_AW);
  float* M  = (float*)(ws + OFF_MS);
  float* I  = (float*)(ws + OFF_MS + 16384);

  const float invXS = 16256.0f / 6.0f;
  const float invWS = 16320.0f / 0.03125f;

  quant_kernel<<<2048, 256, 0, stream>>>(x, XQH, XQL, 8388608, invXS);
  quant_w_kernel<<<1536, 256, 0, stream>>>(Wk, Wq, Wv, WT, invWS);

  gemm_i8<<<6144, 256, 0, stream>>>((const char*)XQH, (const char*)XQL,
                                    WT, bk, bq, bv, K, Q, V);

  logits_kernel<<<BATCH, 256, 0, stream>>>(K, Q, AW);
  stats_kernel<<<NT, 1024, 0, stream>>>(AW, M, I);
  out_kernel<<<BATCH, 512, 0, stream>>>(V, AW, M, I, out);
}

// Round 13
// 303.460 us; speedup vs baseline: 1.2249x; 1.2249x over previous
//
#include <hip/hip_runtime.h>
#include <hip/hip_bf16.h>

// ---------------------------------------------------------------------------
// TileSelfAttention, round 13.
// QKV GEMM = R11 geometry (256x256, 8 waves, dual-digit i8, shift-fold,
// fragment-order LDS, 0 bank conflicts) + TRUE T4: counted vmcnt, never
// draining in the main loop.  Stage one 16KB plane per phase into the next
// buffer; publish each plane with vmcnt(6/6/4) one phase before first read.
// Steady state keeps >=4 loads in flight across every barrier.
// ---------------------------------------------------------------------------

typedef __bf16 bf16;
using i32x4 = __attribute__((ext_vector_type(4))) int;

#define NT     64
#define BATCH  512

#define OFF_XQH 0ul
#define OFF_XQL 33554432ul
#define OFF_WT  67108864ul
#define OFF_K   70254592ul
#define OFF_Q   137363456ul
#define OFF_V   204472320ul
#define OFF_AW  271581184ul
#define OFF_MS  279969792ul

// ---------------------------------------------------------------------------
__global__ void quant_kernel(const float* __restrict__ x,
                             unsigned int* __restrict__ qh,
                             unsigned int* __restrict__ ql, int n4, float invS) {
  int i = blockIdx.x * blockDim.x + threadIdx.x;
  int stride = gridDim.x * blockDim.x;
  for (; i < n4; i += stride) {
    float4 v = ((const float4*)x)[i];
    unsigned hw = 0, lw = 0;
#pragma unroll
    for (int j = 0; j < 4; ++j) {
      float f = (j == 0) ? v.x : (j == 1) ? v.y : (j == 2) ? v.z : v.w;
      int q = __float2int_rn(f * invS);
      q = max(-16320, min(16319, q));
      int h = (q + 64) >> 7;
      int lo = q - (h << 7);
      hw |= ((unsigned)(h & 0xFF)) << (8 * j);
      lw |= ((unsigned)(lo & 0xFF)) << (8 * j);
    }
    qh[i] = hw;
    ql[i] = lw;
  }
}

// ---------------------------------------------------------------------------
__global__ void quant_w_kernel(const float* __restrict__ W0,
                               const float* __restrict__ W1,
                               const float* __restrict__ W2,
                               char* __restrict__ WT, float invS) {
  int gid = blockIdx.x * blockDim.x + threadIdx.x;  // 0..393215
  int proj = gid >> 17;
  int idx = gid & 131071;
  const float* W = (proj == 0) ? W0 : (proj == 1 ? W1 : W2);
  int c = idx >> 8, k = (idx & 255) * 4;
  float4 v = ((const float4*)W)[idx];
  unsigned hw = 0, lw = 0;
#pragma unroll
  for (int j = 0; j < 4; ++j) {
    float f = (j == 0) ? v.x : (j == 1) ? v.y : (j == 2) ? v.z : v.w;
    int q = __float2int_rn(f * invS);
    q = max(-16320, min(16319, q));
    int h = (q + 64) >> 7;
    int lo = q - (h << 7);
    hw |= ((unsigned)(h & 0xFF)) << (8 * j);
    lw |= ((unsigned)(lo & 0xFF)) << (8 * j);
  }
  int kc = k >> 6, kg = (k >> 4) & 3, ki = k & 15;
  int ct = c >> 4, lane = (c & 15) | (kg << 4);
  size_t dst = (size_t)proj * 1048576 + (size_t)(ct * 16 + kc) * 2048 +
               lane * 16 + ki;
  *(unsigned int*)(WT + dst) = hw;          // ph plane
  *(unsigned int*)(WT + dst + 1024) = lw;   // pl plane
}

// ---------------------------------------------------------------------------
__device__ __forceinline__ void gl16(const char* g, char* l) {
  __builtin_amdgcn_global_load_lds(
      (const __attribute__((address_space(1))) unsigned int*)g,
      (__attribute__((address_space(3))) unsigned int*)l, 16, 0, 0);
}

#define VMC(n)  asm volatile("s_waitcnt vmcnt(" #n ")" ::: "memory")
#define LGKM0   asm volatile("s_waitcnt lgkmcnt(0)" ::: "memory")
#define BAR     __builtin_amdgcn_s_barrier()
#define SGB     __builtin_amdgcn_sched_barrier(0)
#define MFMA8   __builtin_amdgcn_mfma_i32_16x16x64_i8

__global__ __launch_bounds__(512, 2) void gemm_i8(
    const char* __restrict__ XQH, const char* __restrict__ XQL,
    const char* __restrict__ WT,
    const float* __restrict__ bk, const float* __restrict__ bq,
    const float* __restrict__ bv,
    float* __restrict__ K, float* __restrict__ Q, float* __restrict__ V) {
  __shared__ __align__(16) char lds[131072];  // 2 x 64KB
  // buffer: Aqh [0,16K) Aql [16K,32K) Bph [32K,48K) Bpl [48K,64K)

  // T1: bijective XCD swizzle (768 = 8 * 96); mt-major for A-panel L2 reuse
  const int bid = (blockIdx.x & 7) * 96 + (blockIdx.x >> 3);
  const int mt = bid / 6, nb = bid % 6;
  const int gm0 = mt * 256;
  const int proj = nb >> 1;
  const int nbl = nb & 1;
  const int wn0 = nbl * 256;

  const int tid = threadIdx.x;
  const int l = tid & 63, w = tid >> 6;
  const int wr = w >> 2, wc = w & 3;   // 8 waves: 2M x 4N, wave tile 128x64
  const int lr = l & 15, lk = l >> 4;

  const char* aqh0 = XQH + (size_t)(gm0 + ((tid >> 6) << 4) + (tid & 15)) * 1024
                         + (((tid >> 4) & 3) << 4);
  const char* aql0 = XQL + (size_t)(gm0 + ((tid >> 6) << 4) + (tid & 15)) * 1024
                         + (((tid >> 4) & 3) << 4);
  const char* wph0 = WT + (size_t)proj * 1048576 +
                     (size_t)(nbl * 16 + (tid >> 6)) * 32768 + (tid & 63) * 16;
  const char* wpl0 = wph0 + 1024;
  const int dT = tid * 16;

  // fragment read bases (wave-sequential 1KB -> conflict-free)
  const int rdA = (wr * 8) * 1024 + l * 16;          // + mf*1024 ; ql +16384
  const int rdB = 32768 + (wc * 4) * 1024 + l * 16;  // + nf*1024 ; pl +16384

  i32x4 acc[8][4] = {};
  const i32x4 Z = {0, 0, 0, 0};

  // per-plane stages (2 x gl16 each), into buffer at byte offset bo
  auto stAqh = [&](int kc, int bo) {
    const int kA = kc * 64;
    gl16(aqh0 + kA, lds + bo + dT);
    gl16(aqh0 + 131072 + kA, lds + bo + 8192 + dT);
  };
  auto stAql = [&](int kc, int bo) {
    const int kA = kc * 64;
    gl16(aql0 + kA, lds + bo + 16384 + dT);
    gl16(aql0 + 131072 + kA, lds + bo + 24576 + dT);
  };
  auto stBph = [&](int kc, int bo) {
    const int kB = kc * 2048;
    gl16(wph0 + kB, lds + bo + 32768 + dT);
    gl16(wph0 + 262144 + kB, lds + bo + 40960 + dT);
  };
  auto stBpl = [&](int kc, int bo) {
    const int kB = kc * 2048;
    gl16(wpl0 + kB, lds + bo + 49152 + dT);
    gl16(wpl0 + 262144 + kB, lds + bo + 57344 + dT);
  };

  // prologue: chunk 0 planes (8 loads); publish Aqh+Bpl (keep Bph,Aql in flight)
  stAqh(0, 0); stBpl(0, 0); stBph(0, 0); stAql(0, 0);
  VMC(4);
  BAR;

  auto chunk = [&](int kc, bool last) {
    const int bo = (kc & 1) * 65536, nbuf = bo ^ 65536;
    i32x4 aHa[4], aHb[4], aLa[4], aLb[4], bH[4], bL[4];

    // ---- P1: reads Aqh[m0-3], Bpl (published @ prev P5); stage next Aqh
#pragma unroll
    for (int m = 0; m < 4; ++m)
      aHa[m] = *(const i32x4*)(lds + bo + rdA + m * 1024);
#pragma unroll
    for (int n = 0; n < 4; ++n)
      bL[n] = *(const i32x4*)(lds + bo + rdB + 16384 + n * 1024);
    if (!last) stAqh(kc + 1, nbuf);
    BAR; LGKM0; SGB;
    __builtin_amdgcn_s_setprio(1);
#pragma unroll
    for (int m = 0; m < 4; ++m)
#pragma unroll
      for (int n = 0; n < 4; ++n)
        acc[m][n] = MFMA8(aHa[m], bL[n], acc[m][n], 0, 0, 0);
    __builtin_amdgcn_s_setprio(0);
    BAR;

    // ---- P2: reads Aqh[m4-7]; stage next Bpl; publish Bph(bo)
#pragma unroll
    for (int m = 0; m < 4; ++m)
      aHb[m] = *(const i32x4*)(lds + bo + rdA + (m + 4) * 1024);
    if (!last) { stBpl(kc + 1, nbuf); VMC(6); } else { VMC(2); }
    BAR; LGKM0; SGB;
    __builtin_amdgcn_s_setprio(1);
#pragma unroll
    for (int m = 0; m < 4; ++m)
#pragma unroll
      for (int n = 0; n < 4; ++n)
        acc[m + 4][n] = MFMA8(aHb[m], bL[n], acc[m + 4][n], 0, 0, 0);
    __builtin_amdgcn_s_setprio(0);
    BAR;

    // ---- P3: reads Bph; stage next Bph; publish Aql(bo)
#pragma unroll
    for (int n = 0; n < 4; ++n)
      bH[n] = *(const i32x4*)(lds + bo + rdB + n * 1024);
    if (!last) { stBph(kc + 1, nbuf); VMC(6); } else { VMC(0); }
    BAR; LGKM0; SGB;
    __builtin_amdgcn_s_setprio(1);
#pragma unroll
    for (int n = 0; n < 4; ++n) {
      i32x4 t0 = MFMA8(aHb[0], bH[n], Z, 0, 0, 0);
      i32x4 t1 = MFMA8(aHb[1], bH[n], Z, 0, 0, 0);
      i32x4 t2 = MFMA8(aHb[2], bH[n], Z, 0, 0, 0);
      i32x4 t3 = MFMA8(aHb[3], bH[n], Z, 0, 0, 0);
      acc[4][n] = acc[4][n] + (t0 << 7);
      acc[5][n] = acc[5][n] + (t1 << 7);
      acc[6][n] = acc[6][n] + (t2 << 7);
      acc[7][n] = acc[7][n] + (t3 << 7);
    }
    __builtin_amdgcn_s_setprio(0);
    BAR;

    // ---- P4: reads Aql[m0-3]; stage next Aql
#pragma unroll
    for (int m = 0; m < 4; ++m)
      aLa[m] = *(const i32x4*)(lds + bo + 16384 + rdA + m * 1024);
    if (!last) stAql(kc + 1, nbuf);
    BAR; LGKM0; SGB;
    __builtin_amdgcn_s_setprio(1);
#pragma unroll
    for (int n = 0; n < 4; ++n) {
      i32x4 t0 = MFMA8(aHa[0], bH[n], Z, 0, 0, 0);
      i32x4 t1 = MFMA8(aHa[1], bH[n], Z, 0, 0, 0);
      i32x4 t2 = MFMA8(aHa[2], bH[n], Z, 0, 0, 0);
      i32x4 t3 = MFMA8(aHa[3], bH[n], Z, 0, 0, 0);
      acc[0][n] = acc[0][n] + (t0 << 7);
      acc[1][n] = acc[1][n] + (t1 << 7);
      acc[2][n] = acc[2][n] + (t2 << 7);
      acc[3][n] = acc[3][n] + (t3 << 7);
    }
    __builtin_amdgcn_s_setprio(0);
    BAR;

    // ---- P5: reads Aql[m4-7]; publish next chunk's Aqh+Bpl
#pragma unroll
    for (int m = 0; m < 4; ++m)
      aLb[m] = *(const i32x4*)(lds + bo + 16384 + rdA + (m + 4) * 1024);
    if (!last) VMC(4);
    BAR; LGKM0; SGB;
    __builtin_amdgcn_s_setprio(1);
#pragma unroll
    for (int m = 0; m < 4; ++m)
#pragma unroll
      for (int n = 0; n < 4; ++n)
        acc[m][n] = MFMA8(aLa[m], bH[n], acc[m][n], 0, 0, 0);
    __builtin_amdgcn_s_setprio(0);
    BAR;

    // ---- P6: register-only
    __builtin_amdgcn_s_setprio(1);
#pragma unroll
    for (int m = 0; m < 4; ++m)
#pragma unroll
      for (int n = 0; n < 4; ++n)
        acc[m + 4][n] = MFMA8(aLb[m], bH[n], acc[m + 4][n], 0, 0, 0);
    __builtin_amdgcn_s_setprio(0);
  };

  for (int kc = 0; kc < 15; ++kc) chunk(kc, false);
  chunk(15, true);

  // epilogue: Out = 128*SC*acc + bias
  const float SCC = 128.0f * (6.0f / 16256.0f) * (0.03125f / 16320.0f);
  const float* bias = (proj == 0) ? bk : (proj == 1 ? bq : bv);
  float* Out = (proj == 0) ? K : (proj == 1 ? Q : V);
#pragma unroll
  for (int m = 0; m < 8; ++m) {
    const int row0 = gm0 + wr * 128 + m * 16 + lk * 4;
#pragma unroll
    for (int n = 0; n < 4; ++n) {
      const int col = wn0 + wc * 64 + n * 16 + lr;
      const float bb = bias[col];
#pragma unroll
      for (int r = 0; r < 4; ++r)
        Out[(size_t)(row0 + r) * 512 + col] =
            SCC * (float)acc[m][n][r] + bb;
    }
  }
}

// ---------------------------------------------------------------------------
// logits: AW[b,t,s] = (1/sqrt(512)) * sum_c K[b*64+t,c] * Q[b*64+s,c]
// ---------------------------------------------------------------------------
__global__ __launch_bounds__(256) void logits_kernel(
    const float* __restrict__ K, const float* __restrict__ Q,
    float* __restrict__ AW) {
  __shared__ float Ks[64][68];
  __shared__ float Qs[64][68];
  const int b = blockIdx.x;
  const float* Kb = K + (size_t)b * 32768;
  const float* Qb = Q + (size_t)b * 32768;
  const int tid = threadIdx.x;
  const int tr = tid >> 4, tc = tid & 15;

  float acc[4][4] = {};
  for (int c0 = 0; c0 < 512; c0 += 64) {
    __syncthreads();
#pragma unroll
    for (int i = 0; i < 4; ++i) {
      int idx = tid + i * 256;
      int row = idx >> 4;
      int c4 = (idx & 15) * 4;
      float4 kv = *(const float4*)&Kb[row * 512 + c0 + c4];
      float4 qv = *(const float4*)&Qb[row * 512 + c0 + c4];
      Ks[c4 + 0][row] = kv.x; Ks[c4 + 1][row] = kv.y;
      Ks[c4 + 2][row] = kv.z; Ks[c4 + 3][row] = kv.w;
      Qs[c4 + 0][row] = qv.x; Qs[c4 + 1][row] = qv.y;
      Qs[c4 + 2][row] = qv.z; Qs[c4 + 3][row] = qv.w;
    }
    __syncthreads();
#pragma unroll 4
    for (int cc = 0; cc < 64; ++cc) {
      float4 kx = *(const float4*)&Ks[cc][tr * 4];
      float4 qx = *(const float4*)&Qs[cc][tc * 4];
#pragma unroll
      for (int i = 0; i < 4; ++i)
#pragma unroll
        for (int j = 0; j < 4; ++j) acc[i][j] += kx[i] * qx[j];
    }
  }
  const float scale = 0.04419417382415922f;
#pragma unroll
  for (int i = 0; i < 4; ++i)
#pragma unroll
    for (int j = 0; j < 4; ++j)
      AW[(size_t)b * 4096 + (tr * 4 + i) * 64 + (tc * 4 + j)] =
          acc[i][j] * scale;
}

// ---------------------------------------------------------------------------
// stats over batch axis: for each (t,s), m = max_b, inv = 1/sum_b exp(l-m).
// ---------------------------------------------------------------------------
__global__ __launch_bounds__(1024) void stats_kernel(
    const float* __restrict__ AW, float* __restrict__ M,
    float* __restrict__ I) {
  __shared__ float red[16][64];
  const int tt = blockIdx.x;
  const int tid = threadIdx.x;
  const int s = tid & 63, bq = tid >> 6;
  const size_t base = (size_t)tt * 64 + s;

  float m = -3.4e38f;
  for (int b = bq * 32; b < bq * 32 + 32; ++b)
    m = fmaxf(m, AW[(size_t)b * 4096 + base]);
  red[bq][s] = m;
  __syncthreads();
#pragma unroll
  for (int i = 0; i < 16; ++i) m = fmaxf(m, red[i][s]);
  __syncthreads();

  float sum = 0.f;
  for (int b = bq * 32; b < bq * 32 + 32; ++b)
    sum += __expf(AW[(size_t)b * 4096 + base] - m);
  red[bq][s] = sum;
  __syncthreads();
  if (bq == 0) {
    sum = 0.f;
#pragma unroll
    for (int i = 0; i < 16; ++i) sum += red[i][s];
    M[tt * 64 + s] = m;
    I[tt * 64 + s] = 1.0f / sum;
  }
}

// ---------------------------------------------------------------------------
// out[b,c,s] = sum_t V[b*64+t, c] * p,  p = exp(AW[b,t,s]-M[t,s])*I[t,s]
// ---------------------------------------------------------------------------
__global__ __launch_bounds__(512) void out_kernel(
    const float* __restrict__ V, const float* __restrict__ AW,
    const float* __restrict__ M, const float* __restrict__ I,
    float* __restrict__ out) {
  __shared__ float Vs[32768];    // [t][c] flat, 128KB
  __shared__ float Ps[64][65];   // 16.25KB
  const int b = blockIdx.x;
  const int tid = threadIdx.x;
  const float* Vb = V + (size_t)b * 32768;
  const float* Pb = AW + (size_t)b * 4096;

#pragma unroll
  for (int j = 0; j < 16; ++j) {
    int u = j * 512 + tid;
    ((float4*)Vs)[u] = ((const float4*)Vb)[u];
  }
  for (int i = tid; i < 4096; i += 512)
    Ps[i >> 6][i & 63] = __expf(Pb[i] - M[i]) * I[i];
  __syncthreads();

  const int s = tid & 63, cw = tid >> 6;  // cw 0..7
  const int c0 = cw * 64;
  float a[64] = {};
  for (int t = 0; t < 64; ++t) {
    float p = Ps[t][s];
    const float4* vr = (const float4*)(Vs + t * 512 + c0);
#pragma unroll
    for (int j = 0; j < 16; ++j) {
      float4 v = vr[j];
      a[4 * j + 0] += v.x * p;
      a[4 * j + 1] += v.y * p;
      a[4 * j + 2] += v.z * p;
      a[4 * j + 3] += v.w * p;
    }
  }
  float* Ob = out + (size_t)b * 32768;
#pragma unroll
  for (int j = 0; j < 64; ++j)
    Ob[(size_t)(c0 + j) * 64 + s] = a[j];
}

// ---------------------------------------------------------------------------
extern "C" void kernel_launch(void* const* d_in, const int* in_sizes, int n_in,
                              void* d_out, int out_size, void* d_ws,
                              size_t ws_size, hipStream_t stream) {
  const float* x  = (const float*)d_in[0];
  const float* Wk = (const float*)d_in[1];
  const float* bk = (const float*)d_in[2];
  const float* Wq = (const float*)d_in[3];
  const float* bq = (const float*)d_in[4];
  const float* Wv = (const float*)d_in[5];
  const float* bv = (const float*)d_in[6];
  float* out = (float*)d_out;

  char* ws = (char*)d_ws;
  unsigned int* XQH = (unsigned int*)(ws + OFF_XQH);
  unsigned int* XQL = (unsigned int*)(ws + OFF_XQL);
  char* WT = ws + OFF_WT;
  float* K  = (float*)(ws + OFF_K);
  float* Q  = (float*)(ws + OFF_Q);
  float* V  = (float*)(ws + OFF_V);
  float* AW = (float*)(ws + OFF_AW);
  float* M  = (float*)(ws + OFF_MS);
  float* I  = (float*)(ws + OFF_MS + 16384);

  const float invXS = 16256.0f / 6.0f;
  const float invWS = 16320.0f / 0.03125f;

  quant_kernel<<<2048, 256, 0, stream>>>(x, XQH, XQL, 8388608, invXS);
  quant_w_kernel<<<1536, 256, 0, stream>>>(Wk, Wq, Wv, WT, invWS);

  gemm_i8<<<768, 512, 0, stream>>>((const char*)XQH, (const char*)XQL,
                                   WT, bk, bq, bv, K, Q, V);

  logits_kernel<<<BATCH, 256, 0, stream>>>(K, Q, AW);
  stats_kernel<<<NT, 1024, 0, stream>>>(AW, M, I);
  out_kernel<<<BATCH, 512, 0, stream>>>(V, AW, M, I, out);
}